// Round 2
// baseline (200.123 us; speedup 1.0000x reference)
//
#include <hip/hip_runtime.h>
#include <hip/hip_bf16.h>
#include <stdint.h>

#define S_LEN 2048
#define NH 16
#define NB_DELTA (2*S_LEN-1)   // 4095
#define PST 72                 // P LDS row stride in bf16 elems (144B = 9*16B, aligned + 4-bank rotate)
#define LOG2E 1.4426950408889634f

typedef __attribute__((ext_vector_type(8))) __bf16 bf16x8;
typedef __attribute__((ext_vector_type(4))) float f32x4;

__device__ __forceinline__ unsigned short f2bf(float f){   // RNE
    union { float f; unsigned int u; } v; v.f = f;
    unsigned int u = v.u;
    return (unsigned short)((u + 0x7FFFu + ((u >> 16) & 1u)) >> 16);
}
__device__ __forceinline__ float bf2f(unsigned short u){
    union { unsigned int u; float f; } v; v.u = ((unsigned int)u) << 16;
    return v.f;
}
__device__ __forceinline__ unsigned int pkbf(float a, float b){   // HW packed cvt (RNE)
    __hip_bfloat162 h = __float22bfloat162_rn(float2{a, b});
    unsigned int u;
    __builtin_memcpy(&u, &h, 4);
    return u;
}
#if __has_builtin(__builtin_amdgcn_exp2f)
__device__ __forceinline__ float fexp2(float x){ return __builtin_amdgcn_exp2f(x); }
#else
__device__ __forceinline__ float fexp2(float x){ return __expf(x * 0.69314718056f); }
#endif

// async global->LDS, 16B per lane; LDS dest = wave-uniform base + lane*16
__device__ __forceinline__ void gload16(const void* g, void* l){
    __builtin_amdgcn_global_load_lds(
        (const __attribute__((address_space(1))) void*)(uintptr_t)g,
        (__attribute__((address_space(3))) void*)(uintptr_t)l, 16, 0, 0);
}

// ---------------- fused prep: z<4 -> transpose+cast W[z]; z==4 -> hs cast + bias table
// biasT is PRE-SCALED: (bias - 16) * log2e  (exp2-softmax form; the -16 cancels in softmax)
__global__ __launch_bounds__(256) void prep_kernel(
    const float* __restrict__ hs, unsigned short* __restrict__ hsb,
    const float* __restrict__ W0, const float* __restrict__ W1,
    const float* __restrict__ W2, const float* __restrict__ W3,
    unsigned short* __restrict__ D0, unsigned short* __restrict__ D1,
    unsigned short* __restrict__ D2, unsigned short* __restrict__ D3,
    const float* __restrict__ rel_bias, float* __restrict__ biasT){
    if (blockIdx.z == 4) {
        int bi = blockIdx.y * 32 + blockIdx.x;   // 0..1023
        for (int it = 0; it < 4; it++) {
            int i = bi * 4096 + it * 1024 + threadIdx.x * 4;
            float4 f = *(const float4*)(hs + i);
            ushort4 o;
            o.x = f2bf(f.x); o.y = f2bf(f.y); o.z = f2bf(f.z); o.w = f2bf(f.w);
            *(ushort4*)(hsb + i) = o;
        }
        if (bi < 16) {
            int t = bi * 256 + threadIdx.x;
            if (t < NB_DELTA) {
                int delta = t - (S_LEN - 1);          // j - i
                int bucket = (delta > 0) ? 16 : 0;
                int a = delta < 0 ? -delta : delta;
                int b;
                if (a < 8) b = a;
                else {
                    int bl = 33 - __builtin_clz(a * a);   // 8 + floor(2*log2(a/8)), exact
                    b = bl < 15 ? bl : 15;
                }
                bucket += b;
                for (int h = 0; h < NH; h++)
                    biasT[h * NB_DELTA + t] = (rel_bias[bucket * NH + h] - 16.f) * LOG2E;
            }
        }
        return;
    }
    const float* src; unsigned short* dst;
    switch (blockIdx.z) {
        case 0: src = W0; dst = D0; break;
        case 1: src = W1; dst = D1; break;
        case 2: src = W2; dst = D2; break;
        default: src = W3; dst = D3; break;
    }
    __shared__ float tile[32][33];
    int bx = blockIdx.x, by = blockIdx.y;
    int tx = threadIdx.x & 31, ty = threadIdx.x >> 5;
    for (int i = 0; i < 4; i++)
        tile[ty + 8*i][tx] = src[(size_t)(by*32 + ty + 8*i) * 1024 + bx*32 + tx];
    __syncthreads();
    for (int i = 0; i < 4; i++)
        dst[(size_t)(bx*32 + ty + 8*i) * 1024 + by*32 + tx] = f2bf(tile[tx][ty + 8*i]);
}

// ---------------- bf16 MFMA GEMM, BK=64, async staging, XOR-granule-swizzled LDS.
// MODE 0: fp32 row-major into C0.
// MODE 1: bf16 row-major into C1 for cols<2048 (Q block pre-scaled by log2e);
//         cols>=2048 (the V block) are written TRANSPOSED into Vt[b*1024+v][s].
template<int MODE, int BM>
__global__ __launch_bounds__(256) void gemm_bt_kernel(const unsigned short* __restrict__ A,
                                                      const unsigned short* __restrict__ BT,
                                                      float* __restrict__ C0,
                                                      unsigned short* __restrict__ C1,
                                                      unsigned short* __restrict__ Vt,
                                                      int Kdim, int ldc){
    constexpr int IT = BM / 32;     // m-tiles per wave
    __shared__ __align__(16) unsigned short As[BM * 64];
    __shared__ __align__(16) unsigned short Bs[128 * 64];
    const int t = threadIdx.x;
    const int wave = t >> 6, lane = t & 63;
    const int quad = lane >> 4, l16 = lane & 15;
    const int wm = (wave >> 1) * (BM / 2), wn = (wave & 1) * 64;
    const size_t row0 = (size_t)blockIdx.y * BM, col0 = (size_t)blockIdx.x * 128;

    const int srow8 = lane >> 3;                 // 0..7: row within the wave's 8-row group
    const int gg = (lane & 7) ^ srow8;           // fetch-side granule remap
    const unsigned short* gA = A  + (row0 + wave * 8 + srow8) * (size_t)Kdim + gg * 8;
    const unsigned short* gB = BT + (col0 + wave * 8 + srow8) * (size_t)Kdim + gg * 8;

    f32x4 acc[IT][4] = {};

    for (int kt = 0; kt < Kdim; kt += 64) {
        for (int p = 0; p < BM / 32; p++)
            gload16(gA + (size_t)(p * 32) * Kdim + kt, &As[(p * 32 + wave * 8) * 64]);
        for (int p = 0; p < 4; p++)
            gload16(gB + (size_t)(p * 32) * Kdim + kt, &Bs[(p * 32 + wave * 8) * 64]);
        __syncthreads();
        bf16x8 a[2][IT], b[2][4];
        for (int ks = 0; ks < 2; ks++) {
            for (int i = 0; i < IT; i++)
                a[ks][i] = *(const bf16x8*)(&As[(wm + i*16 + l16) * 64 + (((ks*4 + quad) ^ (l16 & 7)) * 8)]);
            for (int j = 0; j < 4; j++)
                b[ks][j] = *(const bf16x8*)(&Bs[(wn + j*16 + l16) * 64 + (((ks*4 + quad) ^ (l16 & 7)) * 8)]);
        }
        for (int ks = 0; ks < 2; ks++)
            for (int i = 0; i < IT; i++)
                for (int j = 0; j < 4; j++)
                    acc[i][j] = __builtin_amdgcn_mfma_f32_16x16x32_bf16(a[ks][i], b[ks][j], acc[i][j], 0, 0, 0);
        __syncthreads();
    }
    // C/D layout: col = lane&15, row = quad*4 + reg
    for (int i = 0; i < IT; i++)
        for (int j = 0; j < 4; j++) {
            size_t r0 = row0 + wm + i*16 + quad*4;
            size_t c  = col0 + wn + j*16 + l16;
            if (MODE == 0) {
                for (int r = 0; r < 4; r++)
                    C0[(r0 + r) * ldc + c] = acc[i][j][r];
            } else if (c < 2048) {
                float qs = (c < 1024) ? LOG2E : 1.0f;   // pre-scale Q for exp2 softmax
                for (int r = 0; r < 4; r++)
                    C1[(r0 + r) * ldc + c] = f2bf(acc[i][j][r] * qs);
            } else {
                // V block: write transposed. rows r0..r0+3 are 4 consecutive s -> one 8B store.
                size_t bb = r0 >> 11, s = r0 & 2047;
                ushort4 o;
                o.x = f2bf(acc[i][j][0]); o.y = f2bf(acc[i][j][1]);
                o.z = f2bf(acc[i][j][2]); o.w = f2bf(acc[i][j][3]);
                *(ushort4*)(Vt + ((bb << 10) + (c - 2048)) * 2048 + s) = o;
            }
        }
}

// ---------------- MFMA flash attention v12:
// 8 waves x 256 q, double-buffered K/V prefetch, whole-block bias table.
// NEW vs v11: (a) bias folded into the QK^T MFMA accumulator INIT (no post-add,
// no zero-init); (b) row sums computed by a ones-row MFMA against the P fragments
// (row 0 of rsacc = running row sum; no VALU sum tree, no epilogue shuffles).
__global__ __launch_bounds__(512, 4) void flash12_kernel(
    const unsigned short* __restrict__ qkv,
    const unsigned short* __restrict__ vt,
    const float* __restrict__ biasT,      // pre-scaled (x-16)*log2e
    unsigned short* __restrict__ ctxpb,   // [2][4096][1024] bf16 unnormalized
    float* __restrict__ rsbuf)            // [2][4096][16]  fp32 row sums
{
    const int qt = blockIdx.x, h = blockIdx.y;
    const int b = blockIdx.z >> 1, ck = blockIdx.z & 1;
    const int kt0 = ck << 10;
    const int t = threadIdx.x;
    const int w = t >> 6, lane = t & 63, quad = lane >> 4, l16 = lane & 15;
    const int q0 = qt * 256;

    __shared__ __align__(16) unsigned short Ks[2][64 * 64];   // [token j][dim], swizzled
    __shared__ __align__(16) unsigned short Vs[2][64 * 64];   // [dim d][token], swizzled
    __shared__ __align__(16) unsigned short Pb[256 * PST];    // P^T; Q scratch in prologue
    __shared__ float bias_b[1280];                            // all deltas this block touches

    // ---- prologue: stage Q (256 x 64 bf16) into Pb (Q already log2e-scaled by the GEMM)
    for (int s = 0; s < 4; s++) {
        int g = t + s * 512;
        int r = g >> 3, c = (g & 7) * 8;
        *(int4*)&Pb[r * PST + c] =
            *(const int4*)(qkv + (size_t)(b * S_LEN + q0 + r) * 3072 + h * 64 + c);
    }
    // bias table: delta range [kt0-q0-255, kt0-q0+1023] -> 1279 entries
    {
        const float* bsrc = biasT + h * NB_DELTA + (kt0 - q0 + 1792);   // 2047-255 = 1792
        for (int u = t; u < 1279; u += 512) bias_b[u] = bsrc[u];
    }
    const int srow8 = lane >> 3;
    const int gg = (lane & 7) ^ srow8;           // fetch-side granule remap
    const int swz = (l16 & 7) * 8;
    const unsigned short* kbase = qkv + (size_t)(b * S_LEN + w * 8 + srow8) * 3072 + 1024 + h * 64 + gg * 8;
    const unsigned short* vbase = vt + (size_t)(b * 1024 + h * 64 + w * 8 + srow8) * 2048 + gg * 8;
    // first K/V tile into buffer 0 (8 waves cover all 64 rows: 1 gload each)
    gload16(kbase + (size_t)kt0 * 3072, &Ks[0][(w * 8) * 64]);
    gload16(vbase + kt0,                &Vs[0][(w * 8) * 64]);
    __syncthreads();

    bf16x8 qb[2][2];   // [ks][nt]
    for (int nt = 0; nt < 2; nt++)
        for (int ks = 0; ks < 2; ks++)
            qb[ks][nt] = *(const bf16x8*)&Pb[(w * 32 + nt * 16 + l16) * PST + ks * 32 + quad * 8];

    // ones-row A fragment for the row-sum MFMA: A[m=0][k]=1, rows 1..15 = 0.
    // A-fragment layout: lane holds row = l16, k = quad*8 + 0..7.
    bf16x8 onesA = {};
    if (l16 == 0) {
        const __bf16 one = (__bf16)1.0f;
        for (int e = 0; e < 8; e++) onesA[e] = one;
    }

    f32x4 ctx[4][2] = {};    // ctx^T: [d-tile nd][n-tile nt]
    f32x4 rsacc[2] = {};     // row 0 (quad==0, reg 0) = running row sum per q
    const int ib0 = 255 + quad * 4 - w * 32 - l16;   // + i*64 - nt*16 + nb*16 + r

    int cur = 0;
    for (int i = 0; i < 16; i++) {
        // prefetch next K/V tile into the other buffer (latency hidden under compute)
        if (i < 15) {
            int ktn = kt0 + (i + 1) * 64;
            gload16(kbase + (size_t)ktn * 3072, &Ks[cur ^ 1][(w * 8) * 64]);
            gload16(vbase + ktn,                &Vs[cur ^ 1][(w * 8) * 64]);
        }
        // bias -> accumulator init (replaces zero-init AND the post-MFMA bias add)
        f32x4 st[4][2];
        const int ibt = ib0 + i * 64;
        for (int nt = 0; nt < 2; nt++)
            for (int nb = 0; nb < 4; nb++) {
                const float* bp = &bias_b[ibt - nt * 16 + nb * 16];
                st[nb][nt][0] = bp[0]; st[nb][nt][1] = bp[1];
                st[nb][nt][2] = bp[2]; st[nb][nt][3] = bp[3];
            }
        // S^T = K Q^T + bias : A = K rows (m=j), B = Q (n=q)
        __builtin_amdgcn_s_setprio(1);
        for (int ks = 0; ks < 2; ks++)
            for (int nb = 0; nb < 4; nb++) {
                bf16x8 ka = *(const bf16x8*)&Ks[cur][(nb * 16 + l16) * 64 + (((ks * 4 + quad) * 8) ^ swz)];
                st[nb][0] = __builtin_amdgcn_mfma_f32_16x16x32_bf16(ka, qb[ks][0], st[nb][0], 0, 0, 0);
                st[nb][1] = __builtin_amdgcn_mfma_f32_16x16x32_bf16(ka, qb[ks][1], st[nb][1], 0, 0, 0);
            }
        __builtin_amdgcn_s_setprio(0);
        // exp2 softmax (scores already bias'd and log2e-scaled), pack P^T
        for (int nt = 0; nt < 2; nt++) {
            for (int nb = 0; nb < 4; nb++) {
                float e0 = fexp2(st[nb][nt][0]);
                float e1 = fexp2(st[nb][nt][1]);
                float e2 = fexp2(st[nb][nt][2]);
                float e3 = fexp2(st[nb][nt][3]);
                uint2 pk; pk.x = pkbf(e0, e1); pk.y = pkbf(e2, e3);
                *(uint2*)&Pb[(w * 32 + nt * 16 + l16) * PST + nb * 16 + quad * 4] = pk;
            }
        }
        // ctx^T += Vt . P^T ; row sums via ones-row MFMA (Pb rows wave-private)
        __builtin_amdgcn_s_setprio(1);
        for (int ks = 0; ks < 2; ks++) {
            bf16x8 pb0 = *(const bf16x8*)&Pb[(w * 32 + l16) * PST + ks * 32 + quad * 8];
            bf16x8 pb1 = *(const bf16x8*)&Pb[(w * 32 + 16 + l16) * PST + ks * 32 + quad * 8];
            rsacc[0] = __builtin_amdgcn_mfma_f32_16x16x32_bf16(onesA, pb0, rsacc[0], 0, 0, 0);
            rsacc[1] = __builtin_amdgcn_mfma_f32_16x16x32_bf16(onesA, pb1, rsacc[1], 0, 0, 0);
            for (int nd = 0; nd < 4; nd++) {
                bf16x8 va = *(const bf16x8*)&Vs[cur][(nd * 16 + l16) * 64 + (((ks * 4 + quad) * 8) ^ swz)];
                ctx[nd][0] = __builtin_amdgcn_mfma_f32_16x16x32_bf16(va, pb0, ctx[nd][0], 0, 0, 0);
                ctx[nd][1] = __builtin_amdgcn_mfma_f32_16x16x32_bf16(va, pb1, ctx[nd][1], 0, 0, 0);
            }
        }
        __builtin_amdgcn_s_setprio(0);
        __syncthreads();   // drains prefetch vmcnt (already landed) + guards buffer swap
        cur ^= 1;
    }
    // epilogue: store UNNORMALIZED bf16 partials + fp32 row sums (row 0 of rsacc)
    unsigned short* cp = ctxpb + (size_t)ck * 4096 * 1024;
    for (int nt = 0; nt < 2; nt++) {
        int row = b * S_LEN + q0 + w * 32 + nt * 16 + l16;
        if (quad == 0) rsbuf[((size_t)ck * 4096 + row) * 16 + h] = rsacc[nt][0];
        for (int nd = 0; nd < 4; nd++) {
            uint2 pk;
            pk.x = pkbf(ctx[nd][nt][0], ctx[nd][nt][1]);
            pk.y = pkbf(ctx[nd][nt][2], ctx[nd][nt][3]);
            *(uint2*)&cp[(size_t)row * 1024 + h * 64 + nd * 16 + quad * 4] = pk;
        }
    }
}

// ---------------- combine: ctx_bf16 = (ctx0 + ctx1) / (l0 + l1)
__global__ __launch_bounds__(256) void combine_kernel(const unsigned short* __restrict__ ctxpb,
                                                      const float* __restrict__ rsbuf,
                                                      unsigned short* __restrict__ ctxb){
    int e = blockIdx.x * 256 + threadIdx.x;     // one ushort4 per thread
    int row = e >> 8;
    int c4 = (e & 255) * 4;
    int h = c4 >> 6;
    float l = rsbuf[(size_t)row * 16 + h] + rsbuf[((size_t)4096 + row) * 16 + h];
    ushort4 a  = *(const ushort4*)&ctxpb[(size_t)row * 1024 + c4];
    ushort4 b2 = *(const ushort4*)&ctxpb[(size_t)4096 * 1024 + (size_t)row * 1024 + c4];
    float inv = 1.f / l;
    uint2 o;
    o.x = pkbf((bf2f(a.x) + bf2f(b2.x)) * inv, (bf2f(a.y) + bf2f(b2.y)) * inv);
    o.y = pkbf((bf2f(a.z) + bf2f(b2.z)) * inv, (bf2f(a.w) + bf2f(b2.w)) * inv);
    *(uint2*)&ctxb[(size_t)row * 1024 + c4] = o;
}

extern "C" void kernel_launch(void* const* d_in, const int* in_sizes, int n_in,
                              void* d_out, int out_size, void* d_ws, size_t ws_size,
                              hipStream_t stream) {
    const float* hs       = (const float*)d_in[0];
    const float* Wq       = (const float*)d_in[1];
    const float* Wk       = (const float*)d_in[2];
    const float* Wv       = (const float*)d_in[3];
    const float* Wo       = (const float*)d_in[4];
    const float* rel_bias = (const float*)d_in[5];
    float* out = (float*)d_out;

    char* ws = (char*)d_ws;
    float* biasT          = (float*)ws;           ws += 262144;      // 16*4095*4 (+pad)
    unsigned short* hsb   = (unsigned short*)ws;  ws += 8388608;     // 4096x1024 bf16
    unsigned short* WT    = (unsigned short*)ws;  ws += 6291456;     // [Wq^T|Wk^T|Wv^T] 3072x1024
    unsigned short* WoT   = (unsigned short*)ws;  ws += 2097152;     // 1024x1024 bf16
    unsigned short* qkvb  = (unsigned short*)ws;  ws += 25165824;    // 4096x3072 bf16 (Q|K|- )
    unsigned short* Vtg   = (unsigned short*)ws;  ws += 8388608;     // 2048x2048 bf16
    unsigned short* ctxb  = (unsigned short*)ws;  ws += 8388608;     // 4096x1024 bf16
    unsigned short* ctxpb = (unsigned short*)ws;  ws += 16777216;    // 2 x 4096x1024 bf16
    float* rsbuf          = (float*)ws;                              // 2 x 4096x16 fp32

    prep_kernel<<<dim3(32, 32, 5), 256, 0, stream>>>(
        hs, hsb, Wq, Wk, Wv, Wo,
        WT, WT + 1024 * 1024, WT + 2 * 1024 * 1024, WoT, rel_bias, biasT);

    // Q|K|V projection, BM=128 (m97-class 128x128 tile, 768 blocks = 3/CU)
    gemm_bt_kernel<1, 128><<<dim3(24, 32), 256, 0, stream>>>(hsb, WT, nullptr, qkvb, Vtg, 1024, 3072);
    // attention, split-S x2, 8-wave blocks (512 blocks = 2/CU exact)
    flash12_kernel<<<dim3(S_LEN / 256, NH, 4), 512, 0, stream>>>(qkvb, Vtg, biasT, ctxpb, rsbuf);
    // combine partials -> bf16 ctx
    combine_kernel<<<4096, 256, 0, stream>>>(ctxpb, rsbuf, ctxb);
    // output projection -> fp32 (BM=64: 512 blocks, 2/CU)
    gemm_bt_kernel<0, 64><<<dim3(8, 64), 256, 0, stream>>>(ctxb, WoT, out, nullptr, nullptr, 1024, 1024);
}

// Round 3
// 190.763 us; speedup vs baseline: 1.0491x; 1.0491x over previous
//
#include <hip/hip_runtime.h>
#include <hip/hip_bf16.h>
#include <stdint.h>

#define S_LEN 2048
#define NH 16
#define NB_DELTA (2*S_LEN-1)   // 4095
#define LOG2E 1.4426950408889634f

typedef __attribute__((ext_vector_type(8))) __bf16 bf16x8;
typedef __attribute__((ext_vector_type(4))) float f32x4;

__device__ __forceinline__ unsigned short f2bf(float f){   // RNE
    union { float f; unsigned int u; } v; v.f = f;
    unsigned int u = v.u;
    return (unsigned short)((u + 0x7FFFu + ((u >> 16) & 1u)) >> 16);
}
__device__ __forceinline__ float bf2f(unsigned short u){
    union { unsigned int u; float f; } v; v.u = ((unsigned int)u) << 16;
    return v.f;
}
__device__ __forceinline__ unsigned int pkbf(float a, float b){   // HW packed cvt (RNE)
    __hip_bfloat162 h = __float22bfloat162_rn(float2{a, b});
    unsigned int u;
    __builtin_memcpy(&u, &h, 4);
    return u;
}
#if __has_builtin(__builtin_amdgcn_exp2f)
__device__ __forceinline__ float fexp2(float x){ return __builtin_amdgcn_exp2f(x); }
#else
__device__ __forceinline__ float fexp2(float x){ return __expf(x * 0.69314718056f); }
#endif

// async global->LDS, 16B per lane; LDS dest = wave-uniform base + lane*16
__device__ __forceinline__ void gload16(const void* g, void* l){
    __builtin_amdgcn_global_load_lds(
        (const __attribute__((address_space(1))) void*)(uintptr_t)g,
        (__attribute__((address_space(3))) void*)(uintptr_t)l, 16, 0, 0);
}

// ---------------- fused prep: z<4 -> transpose+cast W[z]; z==4 -> hs cast + bias table
// biasT is PRE-SCALED: (bias - 16) * log2e  (exp2-softmax form; the -16 cancels in softmax)
__global__ __launch_bounds__(256) void prep_kernel(
    const float* __restrict__ hs, unsigned short* __restrict__ hsb,
    const float* __restrict__ W0, const float* __restrict__ W1,
    const float* __restrict__ W2, const float* __restrict__ W3,
    unsigned short* __restrict__ D0, unsigned short* __restrict__ D1,
    unsigned short* __restrict__ D2, unsigned short* __restrict__ D3,
    const float* __restrict__ rel_bias, float* __restrict__ biasT){
    if (blockIdx.z == 4) {
        int bi = blockIdx.y * 32 + blockIdx.x;   // 0..1023
        for (int it = 0; it < 4; it++) {
            int i = bi * 4096 + it * 1024 + threadIdx.x * 4;
            float4 f = *(const float4*)(hs + i);
            ushort4 o;
            o.x = f2bf(f.x); o.y = f2bf(f.y); o.z = f2bf(f.z); o.w = f2bf(f.w);
            *(ushort4*)(hsb + i) = o;
        }
        if (bi < 16) {
            int t = bi * 256 + threadIdx.x;
            if (t < NB_DELTA) {
                int delta = t - (S_LEN - 1);          // j - i
                int bucket = (delta > 0) ? 16 : 0;
                int a = delta < 0 ? -delta : delta;
                int b;
                if (a < 8) b = a;
                else {
                    int bl = 33 - __builtin_clz(a * a);   // 8 + floor(2*log2(a/8)), exact
                    b = bl < 15 ? bl : 15;
                }
                bucket += b;
                for (int h = 0; h < NH; h++)
                    biasT[h * NB_DELTA + t] = (rel_bias[bucket * NH + h] - 16.f) * LOG2E;
            }
        }
        return;
    }
    const float* src; unsigned short* dst;
    switch (blockIdx.z) {
        case 0: src = W0; dst = D0; break;
        case 1: src = W1; dst = D1; break;
        case 2: src = W2; dst = D2; break;
        default: src = W3; dst = D3; break;
    }
    __shared__ float tile[32][33];
    int bx = blockIdx.x, by = blockIdx.y;
    int tx = threadIdx.x & 31, ty = threadIdx.x >> 5;
    for (int i = 0; i < 4; i++)
        tile[ty + 8*i][tx] = src[(size_t)(by*32 + ty + 8*i) * 1024 + bx*32 + tx];
    __syncthreads();
    for (int i = 0; i < 4; i++)
        dst[(size_t)(bx*32 + ty + 8*i) * 1024 + by*32 + tx] = f2bf(tile[tx][ty + 8*i]);
}

// ---------------- bf16 MFMA GEMM, BK=64, async staging, XOR-granule-swizzled LDS.
// MODE 0: fp32 row-major into C0.
// MODE 1: bf16 row-major into C1 for cols<2048 (Q block pre-scaled by log2e);
//         cols>=2048 (the V block) are written TRANSPOSED into Vt[b*1024+v][s].
template<int MODE, int BM>
__global__ __launch_bounds__(256) void gemm_bt_kernel(const unsigned short* __restrict__ A,
                                                      const unsigned short* __restrict__ BT,
                                                      float* __restrict__ C0,
                                                      unsigned short* __restrict__ C1,
                                                      unsigned short* __restrict__ Vt,
                                                      int Kdim, int ldc){
    constexpr int IT = BM / 32;     // m-tiles per wave
    __shared__ __align__(16) unsigned short As[BM * 64];
    __shared__ __align__(16) unsigned short Bs[128 * 64];
    const int t = threadIdx.x;
    const int wave = t >> 6, lane = t & 63;
    const int quad = lane >> 4, l16 = lane & 15;
    const int wm = (wave >> 1) * (BM / 2), wn = (wave & 1) * 64;
    const size_t row0 = (size_t)blockIdx.y * BM, col0 = (size_t)blockIdx.x * 128;

    const int srow8 = lane >> 3;                 // 0..7: row within the wave's 8-row group
    const int gg = (lane & 7) ^ srow8;           // fetch-side granule remap
    const unsigned short* gA = A  + (row0 + wave * 8 + srow8) * (size_t)Kdim + gg * 8;
    const unsigned short* gB = BT + (col0 + wave * 8 + srow8) * (size_t)Kdim + gg * 8;

    f32x4 acc[IT][4] = {};

    for (int kt = 0; kt < Kdim; kt += 64) {
        for (int p = 0; p < BM / 32; p++)
            gload16(gA + (size_t)(p * 32) * Kdim + kt, &As[(p * 32 + wave * 8) * 64]);
        for (int p = 0; p < 4; p++)
            gload16(gB + (size_t)(p * 32) * Kdim + kt, &Bs[(p * 32 + wave * 8) * 64]);
        __syncthreads();
        bf16x8 a[2][IT], b[2][4];
        for (int ks = 0; ks < 2; ks++) {
            for (int i = 0; i < IT; i++)
                a[ks][i] = *(const bf16x8*)(&As[(wm + i*16 + l16) * 64 + (((ks*4 + quad) ^ (l16 & 7)) * 8)]);
            for (int j = 0; j < 4; j++)
                b[ks][j] = *(const bf16x8*)(&Bs[(wn + j*16 + l16) * 64 + (((ks*4 + quad) ^ (l16 & 7)) * 8)]);
        }
        for (int ks = 0; ks < 2; ks++)
            for (int i = 0; i < IT; i++)
                for (int j = 0; j < 4; j++)
                    acc[i][j] = __builtin_amdgcn_mfma_f32_16x16x32_bf16(a[ks][i], b[ks][j], acc[i][j], 0, 0, 0);
        __syncthreads();
    }
    // C/D layout: col = lane&15, row = quad*4 + reg
    for (int i = 0; i < IT; i++)
        for (int j = 0; j < 4; j++) {
            size_t r0 = row0 + wm + i*16 + quad*4;
            size_t c  = col0 + wn + j*16 + l16;
            if (MODE == 0) {
                for (int r = 0; r < 4; r++)
                    C0[(r0 + r) * ldc + c] = acc[i][j][r];
            } else if (c < 2048) {
                float qs = (c < 1024) ? LOG2E : 1.0f;   // pre-scale Q for exp2 softmax
                for (int r = 0; r < 4; r++)
                    C1[(r0 + r) * ldc + c] = f2bf(acc[i][j][r] * qs);
            } else {
                // V block: write transposed. rows r0..r0+3 are 4 consecutive s -> one 8B store.
                size_t bb = r0 >> 11, s = r0 & 2047;
                ushort4 o;
                o.x = f2bf(acc[i][j][0]); o.y = f2bf(acc[i][j][1]);
                o.z = f2bf(acc[i][j][2]); o.w = f2bf(acc[i][j][3]);
                *(ushort4*)(Vt + ((bb << 10) + (c - 2048)) * 2048 + s) = o;
            }
        }
}

// ---------------- MFMA flash attention v13:
// 8 waves x 256 q, double-buffered K/V prefetch, bias as MFMA C-init,
// row sums via ones-row MFMA.
// NEW vs v12: P stays IN REGISTERS -- the C-layout -> B-fragment remap is done
// with permlane32_swap + permlane16_swap (exchange among the 4 lanes sharing
// l16), eliminating the Pb LDS round-trip (8 ds_write_b64 + 4 ds_read_b128 per
// tile per wave AND its write->read latency chain). Q fragments are loaded
// directly from global (one-time, L2-resident) so the Pb buffer is gone:
// LDS 74.7 KB -> ~37 KB.
__global__ __launch_bounds__(512, 4) void flash13_kernel(
    const unsigned short* __restrict__ qkv,
    const unsigned short* __restrict__ vt,
    const float* __restrict__ biasT,      // pre-scaled (x-16)*log2e
    unsigned short* __restrict__ ctxpb,   // [2][4096][1024] bf16 unnormalized
    float* __restrict__ rsbuf)            // [2][4096][16]  fp32 row sums
{
    const int qt = blockIdx.x, h = blockIdx.y;
    const int b = blockIdx.z >> 1, ck = blockIdx.z & 1;
    const int kt0 = ck << 10;
    const int t = threadIdx.x;
    const int w = t >> 6, lane = t & 63, quad = lane >> 4, l16 = lane & 15;
    const int q0 = qt * 256;

    __shared__ __align__(16) unsigned short Ks[2][64 * 64];   // [token j][dim], swizzled
    __shared__ __align__(16) unsigned short Vs[2][64 * 64];   // [dim d][token], swizzled
    __shared__ float bias_b[1280];                            // all deltas this block touches

    // bias table: delta range [kt0-q0-255, kt0-q0+1023] -> 1279 entries
    {
        const float* bsrc = biasT + h * NB_DELTA + (kt0 - q0 + 1792);   // 2047-255 = 1792
        for (int u = t; u < 1279; u += 512) bias_b[u] = bsrc[u];
    }
    const int srow8 = lane >> 3;
    const int gg = (lane & 7) ^ srow8;           // fetch-side granule remap
    const int swz = (l16 & 7) * 8;
    const unsigned short* kbase = qkv + (size_t)(b * S_LEN + w * 8 + srow8) * 3072 + 1024 + h * 64 + gg * 8;
    const unsigned short* vbase = vt + (size_t)(b * 1024 + h * 64 + w * 8 + srow8) * 2048 + gg * 8;
    // first K/V tile into buffer 0 (8 waves cover all 64 rows: 1 gload each)
    gload16(kbase + (size_t)kt0 * 3072, &Ks[0][(w * 8) * 64]);
    gload16(vbase + kt0,                &Vs[0][(w * 8) * 64]);

    // Q fragments straight from global (Q already log2e-scaled by the GEMM)
    bf16x8 qb[2][2];   // [ks][nt]
    {
        const unsigned short* qbase =
            qkv + (size_t)(b * S_LEN + q0 + w * 32 + l16) * 3072 + h * 64 + quad * 8;
        for (int nt = 0; nt < 2; nt++)
            for (int ks = 0; ks < 2; ks++)
                qb[ks][nt] = *(const bf16x8*)(qbase + (size_t)nt * 16 * 3072 + ks * 32);
    }
    __syncthreads();   // bias_b + first K/V tile ready

    // ones-row A fragment for the row-sum MFMA: A[m=0][k]=1, rows 1..15 = 0.
    bf16x8 onesA = {};
    if (l16 == 0) {
        const __bf16 one = (__bf16)1.0f;
        for (int e = 0; e < 8; e++) onesA[e] = one;
    }

    f32x4 ctx[4][2] = {};    // ctx^T: [d-tile nd][n-tile nt]
    f32x4 rsacc[2] = {};     // row 0 (quad==0, reg 0) = running row sum per q
    const int ib0 = 255 + quad * 4 - w * 32 - l16;   // + i*64 - nt*16 + nb*16 + r

    int cur = 0;
    for (int i = 0; i < 16; i++) {
        // prefetch next K/V tile into the other buffer (latency hidden under compute)
        if (i < 15) {
            int ktn = kt0 + (i + 1) * 64;
            gload16(kbase + (size_t)ktn * 3072, &Ks[cur ^ 1][(w * 8) * 64]);
            gload16(vbase + ktn,                &Vs[cur ^ 1][(w * 8) * 64]);
        }
        // bias -> accumulator init (replaces zero-init AND the post-MFMA bias add)
        f32x4 st[4][2];
        const int ibt = ib0 + i * 64;
        for (int nt = 0; nt < 2; nt++)
            for (int nb = 0; nb < 4; nb++) {
                const float* bp = &bias_b[ibt - nt * 16 + nb * 16];
                st[nb][nt][0] = bp[0]; st[nb][nt][1] = bp[1];
                st[nb][nt][2] = bp[2]; st[nb][nt][3] = bp[3];
            }
        // S^T = K Q^T + bias : A = K rows (m=j), B = Q (n=q)
        __builtin_amdgcn_s_setprio(1);
        for (int ks = 0; ks < 2; ks++)
            for (int nb = 0; nb < 4; nb++) {
                bf16x8 ka = *(const bf16x8*)&Ks[cur][(nb * 16 + l16) * 64 + (((ks * 4 + quad) * 8) ^ swz)];
                st[nb][0] = __builtin_amdgcn_mfma_f32_16x16x32_bf16(ka, qb[ks][0], st[nb][0], 0, 0, 0);
                st[nb][1] = __builtin_amdgcn_mfma_f32_16x16x32_bf16(ka, qb[ks][1], st[nb][1], 0, 0, 0);
            }
        __builtin_amdgcn_s_setprio(0);
        // exp2 softmax (scores already bias'd and log2e-scaled), pack to bf16 pairs
        uint2 pk[2][4];   // [nt][nb]: P[j = nb*16+quad*4+{0..3}][q], packed
        for (int nt = 0; nt < 2; nt++)
            for (int nb = 0; nb < 4; nb++) {
                float e0 = fexp2(st[nb][nt][0]);
                float e1 = fexp2(st[nb][nt][1]);
                float e2 = fexp2(st[nb][nt][2]);
                float e3 = fexp2(st[nb][nt][3]);
                pk[nt][nb].x = pkbf(e0, e1);
                pk[nt][nb].y = pkbf(e2, e3);
            }
        // in-register C-layout -> B-fragment remap (exchange among 4 lanes sharing l16):
        // permlane32_swap(X0,X1) -> (A,B); permlane16_swap(A,B) -> (dword0, dword2).
        // x-chain gives dwords {0,2}, y-chain gives dwords {1,3} of the bf16x8.
        __builtin_amdgcn_s_setprio(1);
        for (int ks = 0; ks < 2; ks++) {
            bf16x8 pbf[2];
            for (int nt = 0; nt < 2; nt++) {
                uint2 x0 = pk[nt][2 * ks], x1 = pk[nt][2 * ks + 1];
                auto sA = __builtin_amdgcn_permlane32_swap(x0.x, x1.x, false, false);
                auto sB = __builtin_amdgcn_permlane16_swap(sA[0], sA[1], false, false);
                auto sC = __builtin_amdgcn_permlane32_swap(x0.y, x1.y, false, false);
                auto sD = __builtin_amdgcn_permlane16_swap(sC[0], sC[1], false, false);
                unsigned int u4[4] = {sB[0], sD[0], sB[1], sD[1]};
                __builtin_memcpy(&pbf[nt], u4, 16);
            }
            rsacc[0] = __builtin_amdgcn_mfma_f32_16x16x32_bf16(onesA, pbf[0], rsacc[0], 0, 0, 0);
            rsacc[1] = __builtin_amdgcn_mfma_f32_16x16x32_bf16(onesA, pbf[1], rsacc[1], 0, 0, 0);
            for (int nd = 0; nd < 4; nd++) {
                bf16x8 va = *(const bf16x8*)&Vs[cur][(nd * 16 + l16) * 64 + (((ks * 4 + quad) * 8) ^ swz)];
                ctx[nd][0] = __builtin_amdgcn_mfma_f32_16x16x32_bf16(va, pbf[0], ctx[nd][0], 0, 0, 0);
                ctx[nd][1] = __builtin_amdgcn_mfma_f32_16x16x32_bf16(va, pbf[1], ctx[nd][1], 0, 0, 0);
            }
        }
        __builtin_amdgcn_s_setprio(0);
        __syncthreads();   // drains prefetch vmcnt (already landed) + guards buffer swap
        cur ^= 1;
    }
    // epilogue: store UNNORMALIZED bf16 partials + fp32 row sums (row 0 of rsacc)
    unsigned short* cp = ctxpb + (size_t)ck * 4096 * 1024;
    for (int nt = 0; nt < 2; nt++) {
        int row = b * S_LEN + q0 + w * 32 + nt * 16 + l16;
        if (quad == 0) rsbuf[((size_t)ck * 4096 + row) * 16 + h] = rsacc[nt][0];
        for (int nd = 0; nd < 4; nd++) {
            uint2 pk2;
            pk2.x = pkbf(ctx[nd][nt][0], ctx[nd][nt][1]);
            pk2.y = pkbf(ctx[nd][nt][2], ctx[nd][nt][3]);
            *(uint2*)&cp[(size_t)row * 1024 + h * 64 + nd * 16 + quad * 4] = pk2;
        }
    }
}

// ---------------- combine: ctx_bf16 = (ctx0 + ctx1) / (l0 + l1)
__global__ __launch_bounds__(256) void combine_kernel(const unsigned short* __restrict__ ctxpb,
                                                      const float* __restrict__ rsbuf,
                                                      unsigned short* __restrict__ ctxb){
    int e = blockIdx.x * 256 + threadIdx.x;     // one ushort4 per thread
    int row = e >> 8;
    int c4 = (e & 255) * 4;
    int h = c4 >> 6;
    float l = rsbuf[(size_t)row * 16 + h] + rsbuf[((size_t)4096 + row) * 16 + h];
    ushort4 a  = *(const ushort4*)&ctxpb[(size_t)row * 1024 + c4];
    ushort4 b2 = *(const ushort4*)&ctxpb[(size_t)4096 * 1024 + (size_t)row * 1024 + c4];
    float inv = 1.f / l;
    uint2 o;
    o.x = pkbf((bf2f(a.x) + bf2f(b2.x)) * inv, (bf2f(a.y) + bf2f(b2.y)) * inv);
    o.y = pkbf((bf2f(a.z) + bf2f(b2.z)) * inv, (bf2f(a.w) + bf2f(b2.w)) * inv);
    *(uint2*)&ctxb[(size_t)row * 1024 + c4] = o;
}

extern "C" void kernel_launch(void* const* d_in, const int* in_sizes, int n_in,
                              void* d_out, int out_size, void* d_ws, size_t ws_size,
                              hipStream_t stream) {
    const float* hs       = (const float*)d_in[0];
    const float* Wq       = (const float*)d_in[1];
    const float* Wk       = (const float*)d_in[2];
    const float* Wv       = (const float*)d_in[3];
    const float* Wo       = (const float*)d_in[4];
    const float* rel_bias = (const float*)d_in[5];
    float* out = (float*)d_out;

    char* ws = (char*)d_ws;
    float* biasT          = (float*)ws;           ws += 262144;      // 16*4095*4 (+pad)
    unsigned short* hsb   = (unsigned short*)ws;  ws += 8388608;     // 4096x1024 bf16
    unsigned short* WT    = (unsigned short*)ws;  ws += 6291456;     // [Wq^T|Wk^T|Wv^T] 3072x1024
    unsigned short* WoT   = (unsigned short*)ws;  ws += 2097152;     // 1024x1024 bf16
    unsigned short* qkvb  = (unsigned short*)ws;  ws += 25165824;    // 4096x3072 bf16 (Q|K|- )
    unsigned short* Vtg   = (unsigned short*)ws;  ws += 8388608;     // 2048x2048 bf16
    unsigned short* ctxb  = (unsigned short*)ws;  ws += 8388608;     // 4096x1024 bf16
    unsigned short* ctxpb = (unsigned short*)ws;  ws += 16777216;    // 2 x 4096x1024 bf16
    float* rsbuf          = (float*)ws;                              // 2 x 4096x16 fp32

    prep_kernel<<<dim3(32, 32, 5), 256, 0, stream>>>(
        hs, hsb, Wq, Wk, Wv, Wo,
        WT, WT + 1024 * 1024, WT + 2 * 1024 * 1024, WoT, rel_bias, biasT);

    // Q|K|V projection, BM=64 (1536 blocks = 6/CU; measured faster than BM=128 here)
    gemm_bt_kernel<1, 64><<<dim3(24, 64), 256, 0, stream>>>(hsb, WT, nullptr, qkvb, Vtg, 1024, 3072);
    // attention, split-S x2, 8-wave blocks (512 blocks = 2/CU exact)
    flash13_kernel<<<dim3(S_LEN / 256, NH, 4), 512, 0, stream>>>(qkvb, Vtg, biasT, ctxpb, rsbuf);
    // combine partials -> bf16 ctx
    combine_kernel<<<4096, 256, 0, stream>>>(ctxpb, rsbuf, ctxb);
    // output projection -> fp32 (BM=64: 512 blocks, 2/CU)
    gemm_bt_kernel<0, 64><<<dim3(8, 64), 256, 0, stream>>>(ctxb, WoT, out, nullptr, nullptr, 1024, 1024);
}